// Round 1
// baseline (32487.463 us; speedup 1.0000x reference)
//
#include <hip/hip_runtime.h>
#include <math.h>

// OptNet IPM QP solve, reformulated via Woodbury:
//  M = Q + G^T D G;  M^{-1} = Qi - Qi G^T (Dinv + K)^{-1} G Qi,  K = G Qi G^T
// Per batch-iteration: add diagonal Dinv=s/lam to K, blocked Cholesky (128, BS=16,
// packed lower triangle in LDS), 5 matvecs against shared (L2-resident) matrices.
// Identity G*dz = Dinv .* y removes one matvec; Gz maintained incrementally.

#define ROFFc(i) ((((i)*((i)+1)))>>1)
__device__ __forceinline__ int ROFF(int i){ return (i*(i+1))>>1; }

__device__ __forceinline__ float waveReduceSum(float v){
  #pragma unroll
  for (int o=32;o>0;o>>=1) v += __shfl_down(v,o,64);
  return v;
}
__device__ __forceinline__ float waveReduceMin(float v){
  #pragma unroll
  for (int o=32;o>0;o>>=1) v = fminf(v, __shfl_down(v,o,64));
  return v;
}

// ---- blocked Cholesky on packed lower triangle (n=128, BS=16) ----
// wave0 factors the 16x16 diag block (no block barrier inside; LDS ordering via
// threadfence_block + per-wave in-order DS), thread-per-row panel solve,
// 4x4 register-tiled trailing update.
__device__ void chol_factor(float* tri, int t, int lane, int wid){
  for (int kb=0; kb<8; ++kb){
    const int c0 = kb*16;
    if (wid==0){
      for (int k=0;k<16;++k){
        float piv = tri[ROFF(c0+k)+c0+k];
        piv = fmaxf(piv, 1e-12f);          // NaN guard for ill-conditioned late-IPM A
        float l = sqrtf(piv);
        float linv = 1.0f/l;
        if (lane==0) tri[ROFF(c0+k)+c0+k] = l;
        if (lane>k && lane<16) tri[ROFF(c0+lane)+c0+k] *= linv;
        __threadfence_block();
        #pragma unroll
        for (int e=0;e<4;++e){
          int ee = lane + 64*e;
          int aa = ee>>4, bb = ee&15;
          if (bb>k && aa>=bb){
            float la = tri[ROFF(c0+aa)+c0+k];
            float lb = tri[ROFF(c0+bb)+c0+k];
            tri[ROFF(c0+aa)+c0+bb] -= la*lb;
          }
        }
        __threadfence_block();
      }
    }
    __syncthreads();
    const int rem = 112 - c0;
    if (t < rem){                           // panel solve: row r vs diag block
      const int r = c0+16+t;
      const int rb = ROFF(r)+c0;
      float x[16];
      #pragma unroll
      for (int c=0;c<16;++c){
        float v = tri[rb+c];
        #pragma unroll
        for (int cc=0;cc<c;++cc) v -= x[cc]*tri[ROFF(c0+c)+c0+cc];
        x[c] = v / tri[ROFF(c0+c)+c0+c];
      }
      #pragma unroll
      for (int c=0;c<16;++c) tri[rb+c] = x[c];
    }
    __syncthreads();
    if (rem > 0){                           // trailing update, 4x4 tiles
      const int base = c0+16;
      const int R = rem>>2;
      const int ntile = (R*(R+1))>>1;
      for (int idx=t; idx<ntile; idx+=256){
        int I = (int)((sqrtf(8.f*(float)idx+1.f)-1.f)*0.5f);
        while (((I+1)*(I+2)>>1) <= idx) ++I;
        while (((I*(I+1))>>1) > idx) --I;
        int J = idx - ((I*(I+1))>>1);
        int i0 = base + 4*I, j0 = base + 4*J;
        float Pi[4][16];
        #pragma unroll
        for (int ii=0;ii<4;++ii){
          int rb2 = ROFF(i0+ii)+c0;
          #pragma unroll
          for (int c=0;c<16;++c) Pi[ii][c] = tri[rb2+c];
        }
        float acc[4][4];
        #pragma unroll
        for (int jj=0;jj<4;++jj){
          int rbj = ROFF(j0+jj)+c0;
          float Pj[16];
          #pragma unroll
          for (int c=0;c<16;++c) Pj[c] = tri[rbj+c];
          #pragma unroll
          for (int ii=0;ii<4;++ii){
            float a0=0.f,a1=0.f,a2=0.f,a3=0.f;
            #pragma unroll
            for (int c=0;c<16;c+=4){
              a0 = fmaf(Pi[ii][c+0],Pj[c+0],a0);
              a1 = fmaf(Pi[ii][c+1],Pj[c+1],a1);
              a2 = fmaf(Pi[ii][c+2],Pj[c+2],a2);
              a3 = fmaf(Pi[ii][c+3],Pj[c+3],a3);
            }
            acc[ii][jj] = (a0+a1)+(a2+a3);
          }
        }
        #pragma unroll
        for (int ii=0;ii<4;++ii){
          #pragma unroll
          for (int jj=0;jj<4;++jj){
            int gi=i0+ii, gj=j0+jj;
            if (gi>=gj) tri[ROFF(gi)+gj] -= acc[ii][jj];
          }
        }
      }
    }
    __syncthreads();
  }
}

// forward (L y = rhs) then backward (L^T x = y), blocked BS=16, in place on rhs[128]
__device__ void tri_solve_fb(const float* tri, float* rhs, int t, int lane, int wid){
  for (int kb=0;kb<8;++kb){
    const int c0=kb*16;
    if (wid==0){
      const int c = lane & 15;
      float v = rhs[c0+c];
      #pragma unroll
      for (int cp=0;cp<16;++cp){
        float piv = tri[ROFF(c0+cp)+c0+cp];
        float yv = __shfl(v, cp, 64) / piv;
        if (c>cp)       v -= tri[ROFF(c0+c)+c0+cp]*yv;
        else if (c==cp) v = yv;
      }
      if (lane<16) rhs[c0+lane] = v;
    }
    __syncthreads();
    const int rem = 112-c0;
    if (t<rem){
      const int r = c0+16+t;
      const int rb = ROFF(r)+c0;
      float acc = rhs[r];
      #pragma unroll
      for (int c=0;c<16;++c) acc -= tri[rb+c]*rhs[c0+c];
      rhs[r] = acc;
    }
    __syncthreads();
  }
  for (int kb=7;kb>=0;--kb){
    const int c0=kb*16;
    if (wid==0){
      const int c = lane & 15;
      float v = rhs[c0+c];
      #pragma unroll
      for (int cp=15;cp>=0;--cp){
        float piv = tri[ROFF(c0+cp)+c0+cp];
        float yv = __shfl(v, cp, 64)/piv;
        if (c<cp)       v -= tri[ROFF(c0+cp)+c0+c]*yv;
        else if (c==cp) v = yv;
      }
      if (lane<16) rhs[c0+lane]=v;
    }
    __syncthreads();
    if (t<c0){
      float acc = rhs[t];
      #pragma unroll
      for (int c=0;c<16;++c) acc -= tri[ROFF(c0+c)+t]*rhs[c0+c];
      rhs[t]=acc;
    }
    __syncthreads();
  }
}

// y[r] = sum_j mat[j*128+r] * x[j]   (mat stored so lanes are coalesced over r)
// MODE 0: out=sum ; MODE 1: out = -(e1+e2)+sum ; MODE 2: out = e1 - sum
template<int MODE>
__device__ __forceinline__ void matvecB(const float* __restrict__ mat,
                                        const float* __restrict__ xin,
                                        float* __restrict__ out,
                                        const float* __restrict__ e1,
                                        const float* __restrict__ e2,
                                        float* part, int t){
  const int r = t & 127;
  const int hf = t >> 7;
  const float* mp = mat + (hf<<6)*128 + r;
  const float* xp = xin + (hf<<6);
  float acc = 0.f;
  #pragma unroll 16
  for (int j=0;j<64;++j) acc = fmaf(mp[j*128], xp[j], acc);
  part[t] = acc;
  __syncthreads();
  if (t<128){
    float ssum = part[r] + part[r+128];
    if (MODE==0)      out[r] = ssum;
    else if (MODE==1) out[r] = -(e1[r]+e2[r]) + ssum;
    else              out[r] = e1[r] - ssum;
  }
  __syncthreads();
}

// ---- precompute: chol(Q), then Qi = Q^{-1} and M1 = Qi G^T via multi-RHS solves ----
__global__ __launch_bounds__(256) void k_prep(const float* __restrict__ Q,
        const float* __restrict__ Gm, float* __restrict__ Qi, float* __restrict__ M1)
{
  __shared__ float tri[8256];
  __shared__ unsigned char rowOf[8256];
  __shared__ float Xl[128*32];
  const int t = threadIdx.x;
  const int lane = t&63, wid = t>>6;
  for (int idx=t; idx<8256; idx+=256){
    int i = (int)((sqrtf(8.f*(float)idx+1.f)-1.f)*0.5f);
    while (((i+1)*(i+2)>>1) <= idx) ++i;
    while (((i*(i+1))>>1) > idx) --i;
    rowOf[idx] = (unsigned char)i;
  }
  __syncthreads();
  for (int idx=t; idx<8256; idx+=256){
    int i = rowOf[idx]; int j = idx - ((i*(i+1))>>1);
    tri[idx] = Q[i*128+j];
  }
  __syncthreads();
  chol_factor(tri, t, lane, wid);
  for (int cc=0; cc<8; ++cc){
    const int a0 = (cc&3)*32;
    const bool ident = (cc<4);
    for (int idx=t; idx<4096; idx+=256){
      int i=idx>>5, j=idx&31;
      Xl[idx] = ident ? ((i==(a0+j))?1.f:0.f) : Gm[(a0+j)*128+i];
    }
    __syncthreads();
    for (int kb=0;kb<8;++kb){                    // forward
      const int c0=kb*16;
      if (t<32){
        float x[16];
        #pragma unroll
        for (int c=0;c<16;++c){
          float v = Xl[(c0+c)*32+t];
          #pragma unroll
          for (int cp=0;cp<c;++cp) v -= tri[ROFF(c0+c)+c0+cp]*x[cp];
          x[c] = v/tri[ROFF(c0+c)+c0+c];
        }
        #pragma unroll
        for (int c=0;c<16;++c) Xl[(c0+c)*32+t] = x[c];
      }
      __syncthreads();
      const int rem=112-c0;
      for (int rr=(t>>5); rr<rem; rr+=8){
        const int r=c0+16+rr, j=t&31;
        float acc=Xl[r*32+j];
        #pragma unroll
        for (int c=0;c<16;++c) acc -= tri[ROFF(r)+c0+c]*Xl[(c0+c)*32+j];
        Xl[r*32+j]=acc;
      }
      __syncthreads();
    }
    for (int kb=7;kb>=0;--kb){                   // backward
      const int c0=kb*16;
      if (t<32){
        float x[16];
        #pragma unroll
        for (int c=15;c>=0;--c){
          float v = Xl[(c0+c)*32+t];
          #pragma unroll
          for (int cp=c+1;cp<16;++cp) v -= tri[ROFF(c0+cp)+c0+c]*x[cp];
          x[c] = v/tri[ROFF(c0+c)+c0+c];
        }
        #pragma unroll
        for (int c=0;c<16;++c) Xl[(c0+c)*32+t]=x[c];
      }
      __syncthreads();
      for (int rr=(t>>5); rr<c0; rr+=8){
        const int j=t&31;
        float acc=Xl[rr*32+j];
        #pragma unroll
        for (int c=0;c<16;++c) acc -= tri[ROFF(c0+c)+rr]*Xl[(c0+c)*32+j];
        Xl[rr*32+j]=acc;
      }
      __syncthreads();
    }
    float* dst = ident ? Qi : M1;
    for (int idx=t; idx<4096; idx+=256){
      int i=idx>>5, j=idx&31;
      dst[i*128+a0+j] = Xl[idx];
    }
    __syncthreads();
  }
}

// K = G * M1  (= G Qi G^T), plus its diagonal
__global__ __launch_bounds__(256) void k_kmat(const float* __restrict__ Gm,
        const float* __restrict__ M1, float* __restrict__ K, float* __restrict__ Kd){
  const int idx = blockIdx.x*256 + threadIdx.x;
  const int a = idx>>7, bcol = idx&127;
  float acc=0.f;
  #pragma unroll 8
  for (int j=0;j<128;++j) acc = fmaf(Gm[a*128+j], M1[j*128+bcol], acc);
  K[idx] = acc;
  if (a==bcol) Kd[a]=acc;
}

// ---- main: one block per batch, 20 IPM iterations ----
__global__ __launch_bounds__(256,3) void k_ipm(const float* __restrict__ Q,
      const float* __restrict__ G, const float* __restrict__ p,
      const float* __restrict__ h, const float* __restrict__ Qi,
      const float* __restrict__ M1, const float* __restrict__ K,
      const float* __restrict__ Kd, float* __restrict__ Z)
{
  __shared__ float tri[8256];
  __shared__ unsigned char rowOf[8256];
  __shared__ float sh_z[128], sh_s[128], sh_lam[128], sh_gz[128], sh_qz[128];
  __shared__ float sh_rp[128], sh_rc[128], sh_dinv[128], sh_wm[128];
  __shared__ float sh_rhs[128], sh_t[128], sh_v[128], sh_dz[128];
  __shared__ float sh_p[128], sh_h[128], sh_Kd[128], sh_scl[128];
  __shared__ float part[256];
  __shared__ float red[4];
  const int t = threadIdx.x, b = blockIdx.x;
  const int lane = t & 63, wid = t >> 6;

  for (int idx=t; idx<8256; idx+=256){
    int i = (int)((sqrtf(8.f*(float)idx+1.f)-1.f)*0.5f);
    while (((i+1)*(i+2)>>1) <= idx) ++i;
    while (((i*(i+1))>>1) > idx) --i;
    rowOf[idx] = (unsigned char)i;
  }
  if (t<128){
    sh_z[t]=0.f; sh_gz[t]=0.f; sh_s[t]=1.f; sh_lam[t]=1.f;
    sh_p[t]=p[b*128+t]; sh_h[t]=h[t]; sh_Kd[t]=Kd[t];
  }
  __syncthreads();

  for (int it=0; it<20; ++it){
    // qz = Q z
    matvecB<0>(Q, sh_z, sh_qz, nullptr, nullptr, part, t);
    float s_t=0.f, lam_t=0.f, rp_t=0.f, prod=0.f;
    if (t<128){
      s_t = sh_s[t]; lam_t = sh_lam[t];
      rp_t = sh_gz[t] + s_t - sh_h[t];       // r_p = Gz + s - h (Gz maintained)
      sh_rp[t] = rp_t;
      prod = s_t*lam_t;
    }
    prod = waveReduceSum(prod);
    if (lane==0) red[wid]=prod;
    __syncthreads();
    const float mu = (red[0]+red[1]+red[2]+red[3]) * (1.f/128.f);
    float rc_t=0.f, dinv_t=0.f;
    if (t<128){
      rc_t = s_t*lam_t - 0.1f*mu;            // r_c = s.lam - sigma*mu
      sh_rc[t]=rc_t;
      dinv_t = fminf(s_t/lam_t, 1e30f);      // D^{-1}, overflow-guarded
      sh_dinv[t]=dinv_t;
      float w = (rc_t - lam_t*rp_t)/s_t;
      sh_wm[t] = w - lam_t;
      sh_scl[t] = rsqrtf(sh_Kd[t] + dinv_t); // equilibration scale
    }
    __syncthreads();
    // rhs = -(qz+p) + G^T (w - lam)
    matvecB<1>(G, sh_wm, sh_rhs, sh_qz, sh_p, part, t);
    // tvec = G Qi rhs  (via M1 = Qi G^T, column-major access)
    matvecB<0>(M1, sh_rhs, sh_t, nullptr, nullptr, part, t);
    // build equilibrated A' = S(Dinv+K)S (unit diag) and scale rhs
    if (t<128) sh_t[t] *= sh_scl[t];
    for (int idx=t; idx<8256; idx+=256){
      int i = rowOf[idx];
      int j = idx - ((i*(i+1))>>1);
      float v = (i==j) ? 1.0f : K[i*128+j]*sh_scl[i]*sh_scl[j];
      tri[idx]=v;
    }
    __syncthreads();
    chol_factor(tri, t, lane, wid);
    tri_solve_fb(tri, sh_t, t, lane, wid);
    if (t<128) sh_t[t] *= sh_scl[t];         // y = S y'
    __syncthreads();
    float gdz_t=0.f, ds_t=0.f, dlam_t=0.f;
    if (t<128){
      float y = sh_t[t];
      gdz_t = dinv_t*y;                      // G dz = Dinv .* y (Woodbury identity)
      ds_t = -rp_t - gdz_t;
      dlam_t = (-rc_t - lam_t*ds_t)/s_t;
    }
    // v = rhs - G^T y ;  dz = Qi v
    matvecB<2>(G, sh_t, sh_v, sh_rhs, nullptr, part, t);
    matvecB<0>(Qi, sh_v, sh_dz, nullptr, nullptr, part, t);
    // fraction-to-boundary step
    float ra = 1e9f;
    if (t<128){
      if (ds_t   < 0.f) ra = -s_t/ds_t;
      if (dlam_t < 0.f) ra = fminf(ra, -lam_t/dlam_t);
    }
    ra = waveReduceMin(ra);
    if (lane==0) red[wid]=ra;
    __syncthreads();
    const float rmin = fminf(fminf(red[0],red[1]), fminf(red[2],red[3]));
    const float alpha = fminf(1.0f, 0.99f*rmin);
    if (t<128){
      sh_z[t]  += alpha*sh_dz[t];
      sh_s[t]   = s_t + alpha*ds_t;
      sh_lam[t] = lam_t + alpha*dlam_t;
      sh_gz[t] += alpha*gdz_t;               // Gz incremental
    }
    __syncthreads();
  }
  if (t<128) Z[b*128+t] = sh_z[t];
}

// out = log_softmax(Z.reshape(10, 32768), axis=1)
__global__ __launch_bounds__(1024) void k_logsoftmax(const float* __restrict__ Z,
                                                     float* __restrict__ out){
  __shared__ float red[16];
  __shared__ float sval[2];
  const int r = blockIdx.x, t = threadIdx.x;
  const float* zp = Z + (size_t)r*32768;
  float m = -1e30f;
  for (int i=t;i<32768;i+=1024) m = fmaxf(m, zp[i]);
  #pragma unroll
  for (int o=32;o>0;o>>=1) m = fmaxf(m, __shfl_down(m,o,64));
  if ((t&63)==0) red[t>>6] = m;
  __syncthreads();
  if (t==0){ float mm=red[0]; for (int w=1;w<16;++w) mm=fmaxf(mm,red[w]); sval[0]=mm; }
  __syncthreads();
  const float mx = sval[0];
  float s=0.f;
  for (int i=t;i<32768;i+=1024) s += expf(zp[i]-mx);
  #pragma unroll
  for (int o=32;o>0;o>>=1) s += __shfl_down(s,o,64);
  if ((t&63)==0) red[t>>6]=s;
  __syncthreads();
  if (t==0){ float ss=0.f; for (int w=0;w<16;++w) ss+=red[w]; sval[1]=logf(ss); }
  __syncthreads();
  const float lse = sval[1];
  for (int i=t;i<32768;i+=1024) out[(size_t)r*32768+i] = zp[i]-mx-lse;
}

extern "C" void kernel_launch(void* const* d_in, const int* in_sizes, int n_in,
                              void* d_out, int out_size, void* d_ws, size_t ws_size,
                              hipStream_t stream){
  // inputs: 0=x (unused), 1=Q[128x128], 2=p[2560x128], 3=G[128x128], 4=h[128], 5=m
  const float* Q = (const float*)d_in[1];
  const float* p = (const float*)d_in[2];
  const float* G = (const float*)d_in[3];
  const float* h = (const float*)d_in[4];
  float* ws = (float*)d_ws;
  float* Z  = ws;                 // 327680
  float* Qi = Z + 327680;         // 16384
  float* M1 = Qi + 16384;         // 16384
  float* K  = M1 + 16384;         // 16384
  float* Kd = K + 16384;          // 128
  float* out = (float*)d_out;

  hipLaunchKernelGGL(k_prep, dim3(1), dim3(256), 0, stream, Q, G, Qi, M1);
  hipLaunchKernelGGL(k_kmat, dim3(64), dim3(256), 0, stream, G, M1, K, Kd);
  hipLaunchKernelGGL(k_ipm,  dim3(2560), dim3(256), 0, stream,
                     Q, G, p, h, Qi, M1, K, Kd, Z);
  hipLaunchKernelGGL(k_logsoftmax, dim3(10), dim3(1024), 0, stream, Z, out);
}